// Round 14
// baseline (80.321 us; speedup 1.0000x reference)
//
#include <hip/hip_runtime.h>
#include <math.h>

#define BATCH 4
#define NPTS 8192
#define TB 256
#define XW 32                 // x-cols per wave (NB=1)
#define XSPAN (4 * XW)        // 128 x per block
#define XBLKS (NPTS / XSPAN)  // 64
#define YSPAN 512             // y per block (16 KB LDS -> 8 blocks/CU)
#define YBLKS (NPTS / YSPAN)  // 16
#define YTILES (YSPAN / 32)   // 16

typedef _Float16 f16x8 __attribute__((ext_vector_type(8)));
typedef float f32x16 __attribute__((ext_vector_type(16)));

// ws: unsigned minbits[2][BATCH][NPTS] (256 KB), memset 0xFF (atomicMin identity)
//
// d^2 = x^2 + y^2 - 2 x.y in ONE mfma_f32_32x32x16_f16 (K=16), Dekker f16
// splits (absmax 0.0, R7-R13). Inline-asm MFMA, VGPR C/D, 18-cyc trailing
// nop guard (R9-proven; R11's short variant aborted — never retry).
// R14: minimize live VGPRs (NB=1, no prefetch) + __launch_bounds__(256,8)
// to get under the 64-VGPR occupancy cliff -> 8 waves/SIMD (2x TLP); the
// kernel is latency-bound with both pipes <20% busy (R12/R13 post-mortems).

__device__ __forceinline__ float tree17(f32x16 d, float r) {
    float v0 = fminf(fminf(d[0], d[1]), d[2]);
    float v1 = fminf(fminf(d[3], d[4]), d[5]);
    float v2 = fminf(fminf(d[6], d[7]), d[8]);
    float v3 = fminf(fminf(d[9], d[10]), d[11]);
    float v4 = fminf(fminf(d[12], d[13]), d[14]);
    float w0 = fminf(fminf(v0, v1), v2);
    float w1 = fminf(fminf(v3, v4), d[15]);
    return fminf(fminf(w0, w1), r);  // 8x v_min3_f32
}

#define MFMA1(D0, AF, BF)                                                     \
    asm volatile(                                                             \
        "s_nop 1\n\t"                                                         \
        "v_mfma_f32_32x32x16_f16 %0, %1, %2, %3\n\t"                          \
        "s_nop 7\n\t"                                                         \
        "s_nop 7\n\t"                                                         \
        "s_nop 1\n\t"                                                         \
        : "=&v"(D0)                                                           \
        : "v"(AF), "v"(BF), "v"(zc));

__global__ __launch_bounds__(TB, 8) void hd_mfma(const float* __restrict__ pred,
                                                 const float* __restrict__ gt,
                                                 unsigned* __restrict__ minbits) {
    const int tid = threadIdx.x;
    const int xblk = blockIdx.x % XBLKS;
    const int yblk = blockIdx.x / XBLKS;
    const int b = blockIdx.y;
    const int dir = blockIdx.z;

    const float* X = (dir == 0) ? pred + (size_t)b * NPTS * 3 : gt + (size_t)b * NPTS * 3;
    const float* Y = (dir == 0) ? gt + (size_t)b * NPTS * 3 : pred + (size_t)b * NPTS * 3;

    // Half-major layout (R12-proven): frag-half h of point (t*32+q) at
    //   t*512 + h*256 + q*8 halves — staging writes & frag reads conflict-free.
    __shared__ __align__(16) _Float16 As[YSPAN * 16];  // 16 KB

    // ---- stage A-frags (y-side) into LDS: 2 points per thread ----
    const int ybase = yblk * YSPAN;
    for (int p = tid; p < YSPAN; p += TB) {
        int gp = ybase + p;
        float y0 = Y[3 * gp], y1 = Y[3 * gp + 1], y2 = Y[3 * gp + 2];
        _Float16 h0 = (_Float16)y0, h1 = (_Float16)y1, h2 = (_Float16)y2;
        _Float16 l0 = (_Float16)(y0 - (float)h0);
        _Float16 l1 = (_Float16)(y1 - (float)h1);
        _Float16 l2 = (_Float16)(y2 - (float)h2);
        float ys = fmaf(y0, y0, fmaf(y1, y1, y2 * y2));
        _Float16 sh = (_Float16)ys, sl = (_Float16)(ys - (float)sh);
        const _Float16 n2 = (_Float16)(-2.f);
        _Float16 A0 = n2 * h0, A1 = n2 * h1, A2 = n2 * h2;
        _Float16 C0 = n2 * l0, C1 = n2 * l1, C2 = n2 * l2;
        f16x8 g0 = {A0, A1, A2, A0, A1, A2, C0, C1};                        // k0..7
        f16x8 g1 = {C2, C0, C1, C2, sh, sl, (_Float16)1.f, (_Float16)1.f};  // k8..15
        int t = p >> 5, q = p & 31;
        *(f16x8*)&As[t * 512 + q * 8] = g0;          // h=0 group
        *(f16x8*)&As[t * 512 + 256 + q * 8] = g1;    // h=1 group
    }

    // ---- B-frag (x-side) straight into registers (NB=1) ----
    const int wave = tid >> 6, lane = tid & 63, half = lane >> 5, ln = lane & 31;
    const int xw = xblk * XSPAN + wave * XW;
    f16x8 bf0;
    {
        int px = xw + ln;
        float x0 = X[3 * px], x1 = X[3 * px + 1], x2 = X[3 * px + 2];
        _Float16 h0 = (_Float16)x0, h1 = (_Float16)x1, h2 = (_Float16)x2;
        _Float16 l0 = (_Float16)(x0 - (float)h0);
        _Float16 l1 = (_Float16)(x1 - (float)h1);
        _Float16 l2 = (_Float16)(x2 - (float)h2);
        float xs = fmaf(x0, x0, fmaf(x1, x1, x2 * x2));
        _Float16 sh = (_Float16)xs, sl = (_Float16)(xs - (float)sh);
        f16x8 g0 = {h0, h1, h2, l0, l1, l2, h0, h1};                        // k0..7
        f16x8 g1 = {h2, l0, l1, l2, (_Float16)1.f, (_Float16)1.f, sh, sl};  // k8..15
        bf0 = half ? g1 : g0;
    }
    __syncthreads();

    const f32x16 zc = {0.f, 0.f, 0.f, 0.f, 0.f, 0.f, 0.f, 0.f,
                       0.f, 0.f, 0.f, 0.f, 0.f, 0.f, 0.f, 0.f};
    float rmin0 = 3.0e38f;

    // ---- m-loop: 16 tiles, one ds_read + one MFMA + one tree per iter ----
    int aoff = half * 256 + ln * 8;  // conflict-free: lane stride 16 B
    for (int u = 0; u < YTILES; ++u) {
        f16x8 af = *(const f16x8*)&As[aoff];  // ds_read_b128
        aoff += 512;
        f32x16 d0;
        MFMA1(d0, af, bf0)
        rmin0 = tree17(d0, rmin0);
    }

    // ---- epilogue: merge lane-halves (rows), coalesced atomicMin per col ----
    unsigned* mb = minbits + ((size_t)(dir * BATCH + b)) * NPTS;
    {
        float v = fminf(rmin0, __shfl_xor(rmin0, 32, 64));
        if (lane < 32) atomicMin(&mb[xw + ln], __float_as_uint(fmaxf(v, 0.f)));
    }
}

// One block per batch: max over both directions and all n, then sqrt -> out.
__global__ __launch_bounds__(256) void hd_reduce(const unsigned* __restrict__ minbits,
                                                 float* __restrict__ out) {
    const int tid = threadIdx.x;
    const int b = blockIdx.x;
    const uint4* p0 = (const uint4*)(minbits + (size_t)b * NPTS);
    const uint4* p1 = (const uint4*)(minbits + (size_t)(BATCH + b) * NPTS);
    unsigned vmax = 0u;
    for (int i = tid; i < NPTS / 4; i += 256) {
        uint4 u = p0[i];
        uint4 v = p1[i];
        unsigned a = max(max(u.x, u.y), max(u.z, u.w));
        unsigned c = max(max(v.x, v.y), max(v.z, v.w));
        vmax = max(vmax, max(a, c));
    }
    __shared__ unsigned sm[256];
    sm[tid] = vmax;
    __syncthreads();
    for (int s = 128; s > 0; s >>= 1) {
        if (tid < s) sm[tid] = max(sm[tid], sm[tid + s]);
        __syncthreads();
    }
    if (tid == 0) out[b] = sqrtf(__uint_as_float(sm[0]));
}

extern "C" void kernel_launch(void* const* d_in, const int* in_sizes, int n_in,
                              void* d_out, int out_size, void* d_ws, size_t ws_size,
                              hipStream_t stream) {
    const float* pred = (const float*)d_in[0];  // [B, N, 3]
    const float* gt = (const float*)d_in[1];    // [B, M, 3]
    unsigned* minbits = (unsigned*)d_ws;

    (void)hipMemsetAsync(minbits, 0xFF, (size_t)2 * BATCH * NPTS * sizeof(unsigned),
                         stream);
    hd_mfma<<<dim3(XBLKS * YBLKS, BATCH, 2), TB, 0, stream>>>(pred, gt, minbits);
    hd_reduce<<<BATCH, 256, 0, stream>>>(minbits, (float*)d_out);
}